// Round 23
// baseline (105.632 us; speedup 1.0000x reference)
//
#include <hip/hip_runtime.h>

typedef unsigned short u16;
typedef unsigned int   u32;
typedef unsigned long long u64;
typedef __attribute__((ext_vector_type(8))) short bf16x8;
typedef __attribute__((ext_vector_type(4))) float f32x4;
typedef __attribute__((ext_vector_type(16))) float f32x16;
typedef __attribute__((address_space(3))) u32 lds_u32;
typedef __attribute__((address_space(1))) u32 gbl_u32;

#define MFMA16(a,b,c) __builtin_amdgcn_mfma_f32_16x16x32_bf16((a),(b),(c),0,0,0)
#define MFMA32(a,b,c) __builtin_amdgcn_mfma_f32_32x32x16_bf16((a),(b),(c),0,0,0)
#define QSCALE 0.1803368801111204f   // 0.125 * log2(e)

#define WAIT6 do{ asm volatile("s_waitcnt vmcnt(6)" ::: "memory"); }while(0)
#define WAIT4 do{ asm volatile("s_waitcnt vmcnt(4)" ::: "memory"); }while(0)
#define WAIT3 do{ asm volatile("s_waitcnt vmcnt(3)" ::: "memory"); }while(0)
#define WAIT2 do{ asm volatile("s_waitcnt vmcnt(2)" ::: "memory"); }while(0)
#define WAIT0 do{ asm volatile("s_waitcnt vmcnt(0)" ::: "memory"); }while(0)
#define SCHED __builtin_amdgcn_sched_barrier(0)
#define BARR  __builtin_amdgcn_s_barrier()

__device__ __forceinline__ u16 f2bf(float f){
  u32 u = __builtin_bit_cast(u32, f);
  u32 r = u + 0x7fffu + ((u>>16)&1u);
  return (u16)(r>>16);
}
__device__ __forceinline__ float bf2f(u16 h){
  return __builtin_bit_cast(float, (u32)h<<16);
}

union V8 { u16 s[8]; uint4 v; };

// ---- merged conversions: hs (3072 blocks) + 4 weights (4*288 blocks) ----
__global__ __launch_bounds__(256) void cvt_all(const float* __restrict__ hs,
    const float* __restrict__ Wq, const float* __restrict__ Wk,
    const float* __restrict__ Wv, const float* __restrict__ Wo,
    u16* __restrict__ hsb, u16* __restrict__ wqkv, u16* __restrict__ woh)
{
  const int bid = blockIdx.x;
  if (bid < 3072){
    int i = bid*256 + threadIdx.x;
    const float4* p = (const float4*)(hs + (size_t)i*8);
    float4 a = p[0], b = p[1];
    V8 t;
    t.s[0]=f2bf(a.x); t.s[1]=f2bf(a.y); t.s[2]=f2bf(a.z); t.s[3]=f2bf(a.w);
    t.s[4]=f2bf(b.x); t.s[5]=f2bf(b.y); t.s[6]=f2bf(b.z); t.s[7]=f2bf(b.w);
    *(uint4*)(hsb + (size_t)i*8) = t.v;
    return;
  }
  const int r = bid - 3072;
  const int seg = r / 288;
  const int off = (r - seg*288)*256 + threadIdx.x;
  const float* src = seg==0?Wq: seg==1?Wk: seg==2?Wv: Wo;
  const float4* p = (const float4*)(src + (size_t)off*8);
  float4 a = p[0], b = p[1];
  float xs[8] = {a.x,a.y,a.z,a.w,b.x,b.y,b.z,b.w};
  V8 t;
  #pragma unroll
  for (int j=0;j<8;++j) t.s[j]=f2bf(xs[j]);
  if (seg < 3) *(uint4*)(wqkv + (size_t)seg*589824 + (size_t)off*8) = t.v;
  else         *(uint4*)(woh  + (size_t)off*8) = t.v;
}

// ---- fused QKV GEMM: 128x192 tile, 8 waves, BK=32, 4-buffer depth-3 counted-vmcnt ----
__global__ __launch_bounds__(512) void mm_qkv(const u16* __restrict__ A, const u16* __restrict__ Bp,
    const float* __restrict__ bq, const float* __restrict__ bk, const float* __restrict__ bvv,
    u16* __restrict__ Oq, u16* __restrict__ Ok, u16* __restrict__ Ov)
{
  __shared__ u16 P[4][10240];                 // 4 x 20KB = 80KB (2 blocks/CU)
  const int bid = blockIdx.x;                 // 768
  const int sid = (bid & 7)*96 + (bid >> 3);  // XCD swizzle, m-major per XCD
  const int mb = sid/12, nb = sid - mb*12;
  const int m0 = mb*128, n0 = nb*192;
  const int tid = threadIdx.x;                // 0..511
  const int lane = tid&63, wid = tid>>6;      // 8 waves
  const int wm = wid>>2, wn = wid&3;          // 2m x 4n, wave tile 64x48
  const int fr = lane&15, fg = lane>>4;

  const char* Ab = (const char*)A;
  const char* Bb = (const char*)Bp;
  const char* sp[3];
  int ldst[3];
  #pragma unroll
  for (int c=0;c<3;++c){
    int ci = c*512 + tid;
    if (c==2) ci = 1024 + tid;
    if (ci < 512){
      int line = ci>>3, slot = ci&7;
      int d = slot ^ (line&7);
      int row = 2*line + (d>>2);
      sp[c] = Ab + (size_t)(m0+row)*1536 + (d&3)*16;
    } else if (ci < 1280){
      int i = ci - 512;
      int line = i>>3, slot = i&7;
      int d = slot ^ (line&7);
      int row = 2*line + (d>>2);
      sp[c] = Bb + (size_t)(n0+row)*1536 + (d&3)*16;
    } else {
      sp[c] = Ab;
    }
    ldst[c] = ci*16;
  }

  const int sl = (((fr&1)<<2) + fg) ^ (fr>>1);
  const int aoff = (fr&~1)*64 + sl*16 + wm*4096;
  const int boff = 8192 + (fr&~1)*64 + sl*16 + wn*3072;

  f32x4 zz = {0.f,0.f,0.f,0.f};
  f32x4 acc[4][3];
  #pragma unroll
  for (int i=0;i<4;++i)
    #pragma unroll
    for (int j=0;j<3;++j) acc[i][j]=zz;

  auto STAGE = [&](int t, int b){
    char* dst0 = (char*)P[b];
    #pragma unroll
    for (int c=0;c<3;++c){
      if (c==2 && wid>=4) break;
      __builtin_amdgcn_global_load_lds((const gbl_u32*)(sp[c] + (size_t)t*64),
        (lds_u32*)(dst0 + ldst[c]), 16, 0, 0);
    }
  };
  auto COMPUTE = [&](int b){
    const char* pb = (const char*)P[b];
    bf16x8 bfr[3];
    #pragma unroll
    for (int nt=0;nt<3;++nt)
      bfr[nt] = *(const bf16x8*)(pb + boff + nt*1024);
    #pragma unroll
    for (int mt=0;mt<4;++mt){
      bf16x8 af = *(const bf16x8*)(pb + aoff + mt*1024);
      #pragma unroll
      for (int nt=0;nt<3;++nt)
        acc[mt][nt] = MFMA16(af, bfr[nt], acc[mt][nt]);
    }
  };

  STAGE(0, 0); STAGE(1, 1); STAGE(2, 2);
  for (int t=0; t<24; ++t){
    if (t < 22){ if (wid < 4) WAIT6; else WAIT4; }
    else if (t == 22){ if (wid < 4) WAIT3; else WAIT2; }
    else WAIT0;
    BARR; SCHED;
    if (t < 21) STAGE(t+3, (t+3)&3);
    __builtin_amdgcn_s_setprio(1);
    COMPUTE(t&3);
    __builtin_amdgcn_s_setprio(0);
  }

  const int seg = nb/4;
  const float* bias = seg==0?bq: seg==1?bk:bvv;
  const float sc = (seg==0) ? QSCALE : 1.0f;
  if (seg < 2){
    u16* O = seg==0?Oq:Ok;
    #pragma unroll
    for (int mt=0;mt<4;++mt){
      #pragma unroll
      for (int nt=0;nt<3;++nt){
        int colw = n0 + wn*48 + nt*16 + fr - seg*768;
        float bz = bias[colw];
        int hh = colw>>6, d = colw&63;
        #pragma unroll
        for (int rr=0;rr<4;++rr){
          int row = m0 + wm*64 + mt*16 + fg*4 + rr;
          int b = row>>10, nn = row&1023;
          O[((size_t)(b*12+hh)<<16) + (size_t)nn*64 + d] = f2bf((acc[mt][nt][rr] + bz) * sc);
        }
      }
    }
  } else {
    #pragma unroll
    for (int mt=0;mt<4;++mt){
      #pragma unroll
      for (int nt=0;nt<3;++nt){
        int colw = n0 + wn*48 + nt*16 + fr - 1536;
        float bz = bias[colw];
        int hh = colw>>6, d = colw&63;
        int row0 = m0 + wm*64 + mt*16 + fg*4;
        int b = row0>>10, nn = row0&1023;
        union { u16 h[4]; u64 q; } pk;
        #pragma unroll
        for (int rr=0;rr<4;++rr) pk.h[rr] = f2bf(acc[mt][nt][rr] + bz);
        *(u64*)&Ov[((size_t)(b*12+hh)<<16) + (size_t)d*1024 + nn] = pk.q;
      }
    }
  }
}

// ---- O-projection GEMM: 128x192 tile, 8 waves, 256 blocks = 1/CU, depth-3 ----
__global__ __launch_bounds__(512) void mm_o(const u16* __restrict__ A, const u16* __restrict__ Bp,
                                            const float* __restrict__ bias, float* __restrict__ O)
{
  __shared__ u16 P[4][10240];                 // 4 x 20KB
  const int bid = blockIdx.x;                 // 256
  const int sid = (bid & 7)*32 + (bid >> 3);  // XCD swizzle, m-major per XCD
  const int mb = sid/4, nb = sid & 3;
  const int m0 = mb*128, n0 = nb*192;
  const int tid = threadIdx.x;                // 0..511
  const int lane = tid&63, wid = tid>>6;
  const int wm = wid>>2, wn = wid&3;          // wave tile 64x48
  const int fr = lane&15, fg = lane>>4;

  const char* Ab = (const char*)A;
  const char* Bb = (const char*)Bp;
  const char* sp[3];
  int ldst[3];
  #pragma unroll
  for (int c=0;c<3;++c){
    int ci = c*512 + tid;
    if (c==2) ci = 1024 + tid;
    if (ci < 512){
      int line = ci>>3, slot = ci&7;
      int d = slot ^ (line&7);
      int row = 2*line + (d>>2);
      sp[c] = Ab + (size_t)(m0+row)*1536 + (d&3)*16;
    } else if (ci < 1280){
      int i = ci - 512;
      int line = i>>3, slot = i&7;
      int d = slot ^ (line&7);
      int row = 2*line + (d>>2);
      sp[c] = Bb + (size_t)(n0+row)*1536 + (d&3)*16;
    } else {
      sp[c] = Ab;
    }
    ldst[c] = ci*16;
  }

  const int sl = (((fr&1)<<2) + fg) ^ (fr>>1);
  const int aoff = (fr&~1)*64 + sl*16 + wm*4096;
  const int boff = 8192 + (fr&~1)*64 + sl*16 + wn*3072;

  f32x4 zz = {0.f,0.f,0.f,0.f};
  f32x4 acc[4][3];
  #pragma unroll
  for (int i=0;i<4;++i)
    #pragma unroll
    for (int j=0;j<3;++j) acc[i][j]=zz;

  auto STAGE = [&](int t, int b){
    char* dst0 = (char*)P[b];
    #pragma unroll
    for (int c=0;c<3;++c){
      if (c==2 && wid>=4) break;
      __builtin_amdgcn_global_load_lds((const gbl_u32*)(sp[c] + (size_t)t*64),
        (lds_u32*)(dst0 + ldst[c]), 16, 0, 0);
    }
  };
  auto COMPUTE = [&](int b){
    const char* pb = (const char*)P[b];
    bf16x8 bfr[3];
    #pragma unroll
    for (int nt=0;nt<3;++nt)
      bfr[nt] = *(const bf16x8*)(pb + boff + nt*1024);
    #pragma unroll
    for (int mt=0;mt<4;++mt){
      bf16x8 af = *(const bf16x8*)(pb + aoff + mt*1024);
      #pragma unroll
      for (int nt=0;nt<3;++nt)
        acc[mt][nt] = MFMA16(af, bfr[nt], acc[mt][nt]);
    }
  };

  STAGE(0, 0); STAGE(1, 1); STAGE(2, 2);
  for (int t=0; t<24; ++t){
    if (t < 22){ if (wid < 4) WAIT6; else WAIT4; }
    else if (t == 22){ if (wid < 4) WAIT3; else WAIT2; }
    else WAIT0;
    BARR; SCHED;
    if (t < 21) STAGE(t+3, (t+3)&3);
    __builtin_amdgcn_s_setprio(1);
    COMPUTE(t&3);
    __builtin_amdgcn_s_setprio(0);
  }

  #pragma unroll
  for (int mt=0;mt<4;++mt){
    #pragma unroll
    for (int nt=0;nt<3;++nt){
      int colb = n0 + wn*48 + nt*16 + fr;
      float bz = bias[colb];
      #pragma unroll
      for (int rr=0;rr<4;++rr){
        int row = m0 + wm*64 + mt*16 + fg*4 + rr;
        O[(size_t)row*768 + colb] = acc[mt][nt][rr] + bz;
      }
    }
  }
}

// ---- MFMA flash attention: r21 version (passing) — 32x32 MFMA, in-register P,
// double-buffered K/V, __syncthreads per iter ----
__global__ __launch_bounds__(256, 3) void attn(const u16* __restrict__ qh, const u16* __restrict__ kh,
                                               const u16* __restrict__ vh, u16* __restrict__ ch)
{
  __shared__ u16 Kb[2][4096];          // 16KB
  __shared__ u16 Vb[2][4096];          // 16KB
  const int tid=threadIdx.x, w=tid>>6, lane=tid&63;
  const int l31 = lane&31, h = lane>>5;
  const int bh=blockIdx.x, qt=blockIdx.y;
  const size_t base=(size_t)bh<<16;
  const int q0=qt*128 + w*32;

  const char* kbase = (const char*)(kh + base);
  const char* vbase = (const char*)(vh + base);

  int koff[2], voff[2];
  #pragma unroll
  for (int c=0;c<2;++c){
    int ci = c*256 + tid;
    int row = ci>>3;
    int colp = ((ci&7)*16) ^ ((row&7)<<4);
    koff[c] = row*128  + colp;
    voff[c] = row*2048 + colp;
  }

  // Q B-frags: lane holds Q[d=16*ks+8h+e][q=q0+l31]
  bf16x8 qf[4];
  #pragma unroll
  for (int ks=0;ks<4;++ks)
    qf[ks] = *(const bf16x8*)&qh[base + (size_t)(q0+l31)*64 + ks*16 + h*8];

  const int swz3 = (lane&7)<<4;
  const int dbase = (h<<4) ^ swz3;
  const int krow = l31*128;

  const short one_bf = (short)0x3F80;
  bf16x8 ones = {one_bf,one_bf,one_bf,one_bf,one_bf,one_bf,one_bf,one_bf};

  f32x16 z16 = {0.f,0.f,0.f,0.f,0.f,0.f,0.f,0.f,0.f,0.f,0.f,0.f,0.f,0.f,0.f,0.f};
  f32x16 o0 = z16, o1 = z16, ol = z16;

  {
    #pragma unroll
    for (int c=0;c<2;++c){
      __builtin_amdgcn_global_load_lds((const gbl_u32*)(kbase + koff[c]),
        (lds_u32*)((char*)&Kb[0][0] + c*4096 + w*1024), 16, 0, 0);
      __builtin_amdgcn_global_load_lds((const gbl_u32*)(vbase + voff[c]),
        (lds_u32*)((char*)&Vb[0][0] + c*4096 + w*1024), 16, 0, 0);
    }
  }
  __syncthreads();

  for (int kt=0; kt<16; ++kt){
    const int buf = kt & 1;
    {
      const int ktn = (kt+1) & 15;
      const char* kt_ = kbase + ktn*8192;
      const char* vt_ = vbase + ktn*128;
      #pragma unroll
      for (int c=0;c<2;++c){
        __builtin_amdgcn_global_load_lds((const gbl_u32*)(kt_ + koff[c]),
          (lds_u32*)((char*)&Kb[buf^1][0] + c*4096 + w*1024), 16, 0, 0);
        __builtin_amdgcn_global_load_lds((const gbl_u32*)(vt_ + voff[c]),
          (lds_u32*)((char*)&Vb[buf^1][0] + c*4096 + w*1024), 16, 0, 0);
      }
    }

    // QK^T (swapped): s over 4 d-ksteps
    const char* kb_ = (const char*)&Kb[buf][0];
    f32x16 s0 = z16, s1 = z16;
    __builtin_amdgcn_s_setprio(1);
    #pragma unroll
    for (int ks=0;ks<4;++ks){
      int db = dbase ^ (ks<<5);
      bf16x8 kf0 = *(const bf16x8*)(kb_ + krow + db);
      bf16x8 kf1 = *(const bf16x8*)(kb_ + 4096 + krow + db);
      s0 = MFMA32(kf0, qf[ks], s0);
      s1 = MFMA32(kf1, qf[ks], s1);
    }
    __builtin_amdgcn_s_setprio(0);

    // exp2 + pack + permlane32 swap -> 4 PV A-frags, all in-register
    bf16x8 paf[2][2];
    #pragma unroll
    for (int kbi=0;kbi<2;++kbi){
      const f32x16& sb = kbi ? s1 : s0;
      #pragma unroll
      for (int kp=0;kp<2;++kp){
        float e0 = __builtin_amdgcn_exp2f(sb[kp*8+0]);
        float e1 = __builtin_amdgcn_exp2f(sb[kp*8+1]);
        float e2 = __builtin_amdgcn_exp2f(sb[kp*8+2]);
        float e3 = __builtin_amdgcn_exp2f(sb[kp*8+3]);
        float e4 = __builtin_amdgcn_exp2f(sb[kp*8+4]);
        float e5 = __builtin_amdgcn_exp2f(sb[kp*8+5]);
        float e6 = __builtin_amdgcn_exp2f(sb[kp*8+6]);
        float e7 = __builtin_amdgcn_exp2f(sb[kp*8+7]);
        u32 x, y, uu, vv;
        asm("v_cvt_pk_bf16_f32 %0, %1, %2" : "=v"(x)  : "v"(e0), "v"(e1));
        asm("v_cvt_pk_bf16_f32 %0, %1, %2" : "=v"(y)  : "v"(e2), "v"(e3));
        asm("v_cvt_pk_bf16_f32 %0, %1, %2" : "=v"(uu) : "v"(e4), "v"(e5));
        asm("v_cvt_pk_bf16_f32 %0, %1, %2" : "=v"(vv) : "v"(e6), "v"(e7));
        asm volatile("v_permlane32_swap_b32 %0, %1" : "+v"(x), "+v"(uu));
        asm volatile("v_permlane32_swap_b32 %0, %1" : "+v"(y), "+v"(vv));
        union { u32 u[4]; bf16x8 v; } fx;
        fx.u[0]=x; fx.u[1]=y; fx.u[2]=uu; fx.u[3]=vv;
        paf[kbi][kp] = fx.v;
      }
    }

    // PV + ones (l) on 32x32
    const char* vb_ = (const char*)&Vb[buf][0];
    __builtin_amdgcn_s_setprio(1);
    #pragma unroll
    for (int kbi=0;kbi<2;++kbi){
      #pragma unroll
      for (int kp=0;kp<2;++kp){
        int vcol = dbase ^ (kp<<5) ^ (kbi<<6);
        bf16x8 vf0 = *(const bf16x8*)(vb_ + l31*128 + vcol);
        bf16x8 vf1 = *(const bf16x8*)(vb_ + (32+l31)*128 + vcol);
        o0 = MFMA32(paf[kbi][kp], vf0, o0);
        o1 = MFMA32(paf[kbi][kp], vf1, o1);
        ol = MFMA32(paf[kbi][kp], ones, ol);
      }
    }
    __builtin_amdgcn_s_setprio(0);

    __syncthreads();
  }

  const int b=bh/12, hd=bh%12;
  float inv[16];
  #pragma unroll
  for (int rg=0;rg<16;++rg) inv[rg] = 1.0f / ol[rg];
  #pragma unroll
  for (int nt=0;nt<2;++nt){
    #pragma unroll
    for (int rg=0;rg<16;++rg){
      int q = q0 + (rg&3) + 8*(rg>>2) + 4*h;
      int d = nt*32 + l31;
      float val = (nt ? o1[rg] : o0[rg]) * inv[rg];
      ch[((size_t)b*1024 + q)*768 + hd*64 + d] = f2bf(val);
    }
  }
}

extern "C" void kernel_launch(void* const* d_in, const int* in_sizes, int n_in,
                              void* d_out, int out_size, void* d_ws, size_t ws_size,
                              hipStream_t stream) {
  const float* hs = (const float*)d_in[0];
  const float* Wq = (const float*)d_in[1];
  const float* bq = (const float*)d_in[2];
  const float* Wk = (const float*)d_in[3];
  const float* bk = (const float*)d_in[4];
  const float* Wv = (const float*)d_in[5];
  const float* bv = (const float*)d_in[6];
  const float* Wo = (const float*)d_in[7];
  const float* bo = (const float*)d_in[8];
  float* out = (float*)d_out;

  const size_t PS = (size_t)8192*768;
  u16* ws16  = (u16*)d_ws;
  u16* hs_bf = ws16;                        // reused as c_hi after mm_qkv
  u16* q_bf  = ws16 + PS;
  u16* k_bf  = ws16 + 2*PS;
  u16* v_bf  = ws16 + 3*PS;                 // transposed per head [bh][d][n]
  u16* wqkv  = ws16 + 4*PS;
  u16* woh   = wqkv + 3*589824;
  u16* c_hi  = hs_bf;

  dim3 blk(256);
  cvt_all<<<3072 + 4*288, blk, 0, stream>>>(hs, Wq, Wk, Wv, Wo, hs_bf, wqkv, woh);
  mm_qkv<<<768, dim3(512), 0, stream>>>(hs_bf, wqkv, bq, bk, bv, q_bf, k_bf, v_bf);
  attn<<<dim3(96,8), blk, 0, stream>>>(q_bf, k_bf, v_bf, c_hi);
  mm_o<<<256, dim3(512), 0, stream>>>(c_hi, woh, bo, out);
}

// Round 24
// 104.368 us; speedup vs baseline: 1.0121x; 1.0121x over previous
//
#include <hip/hip_runtime.h>

typedef unsigned short u16;
typedef unsigned int   u32;
typedef unsigned long long u64;
typedef __attribute__((ext_vector_type(8))) short bf16x8;
typedef __attribute__((ext_vector_type(4))) float f32x4;
typedef __attribute__((ext_vector_type(16))) float f32x16;
typedef __attribute__((address_space(3))) u32 lds_u32;
typedef __attribute__((address_space(1))) u32 gbl_u32;

#define MFMA16(a,b,c) __builtin_amdgcn_mfma_f32_16x16x32_bf16((a),(b),(c),0,0,0)
#define MFMA32(a,b,c) __builtin_amdgcn_mfma_f32_32x32x16_bf16((a),(b),(c),0,0,0)
#define QSCALE 0.1803368801111204f   // 0.125 * log2(e)

#define WAIT3 do{ asm volatile("s_waitcnt vmcnt(3)" ::: "memory"); }while(0)
#define WAIT2 do{ asm volatile("s_waitcnt vmcnt(2)" ::: "memory"); }while(0)
#define WAIT0 do{ asm volatile("s_waitcnt vmcnt(0)" ::: "memory"); }while(0)
#define SCHED __builtin_amdgcn_sched_barrier(0)
#define BARR  __builtin_amdgcn_s_barrier()

__device__ __forceinline__ u16 f2bf(float f){
  u32 u = __builtin_bit_cast(u32, f);
  u32 r = u + 0x7fffu + ((u>>16)&1u);
  return (u16)(r>>16);
}
__device__ __forceinline__ float bf2f(u16 h){
  return __builtin_bit_cast(float, (u32)h<<16);
}

union V8 { u16 s[8]; uint4 v; };

// ---- merged conversions: hs (3072 blocks) + 4 weights (4*288 blocks) ----
__global__ __launch_bounds__(256) void cvt_all(const float* __restrict__ hs,
    const float* __restrict__ Wq, const float* __restrict__ Wk,
    const float* __restrict__ Wv, const float* __restrict__ Wo,
    u16* __restrict__ hsb, u16* __restrict__ wqkv, u16* __restrict__ woh)
{
  const int bid = blockIdx.x;
  if (bid < 3072){
    int i = bid*256 + threadIdx.x;
    const float4* p = (const float4*)(hs + (size_t)i*8);
    float4 a = p[0], b = p[1];
    V8 t;
    t.s[0]=f2bf(a.x); t.s[1]=f2bf(a.y); t.s[2]=f2bf(a.z); t.s[3]=f2bf(a.w);
    t.s[4]=f2bf(b.x); t.s[5]=f2bf(b.y); t.s[6]=f2bf(b.z); t.s[7]=f2bf(b.w);
    *(uint4*)(hsb + (size_t)i*8) = t.v;
    return;
  }
  const int r = bid - 3072;
  const int seg = r / 288;
  const int off = (r - seg*288)*256 + threadIdx.x;
  const float* src = seg==0?Wq: seg==1?Wk: seg==2?Wv: Wo;
  const float4* p = (const float4*)(src + (size_t)off*8);
  float4 a = p[0], b = p[1];
  float xs[8] = {a.x,a.y,a.z,a.w,b.x,b.y,b.z,b.w};
  V8 t;
  #pragma unroll
  for (int j=0;j<8;++j) t.s[j]=f2bf(xs[j]);
  if (seg < 3) *(uint4*)(wqkv + (size_t)seg*589824 + (size_t)off*8) = t.v;
  else         *(uint4*)(woh  + (size_t)off*8) = t.v;
}

// ---- fused QKV GEMM: 128x192 tile, 8 waves, BK=32, 3-buffer counted-vmcnt ----
__global__ __launch_bounds__(512) void mm_qkv(const u16* __restrict__ A, const u16* __restrict__ Bp,
    const float* __restrict__ bq, const float* __restrict__ bk, const float* __restrict__ bvv,
    u16* __restrict__ Oq, u16* __restrict__ Ok, u16* __restrict__ Ov)
{
  __shared__ u16 P[3][10240];                 // 3 x 20KB
  const int bid = blockIdx.x;                 // 768
  const int sid = (bid & 7)*96 + (bid >> 3);  // XCD swizzle, m-major per XCD
  const int mb = sid/12, nb = sid - mb*12;
  const int m0 = mb*128, n0 = nb*192;
  const int tid = threadIdx.x;                // 0..511
  const int lane = tid&63, wid = tid>>6;      // 8 waves
  const int wm = wid>>2, wn = wid&3;          // 2m x 4n, wave tile 64x48
  const int fr = lane&15, fg = lane>>4;

  const char* Ab = (const char*)A;
  const char* Bb = (const char*)Bp;
  const char* sp[3];
  int ldst[3];
  #pragma unroll
  for (int c=0;c<3;++c){
    int ci = c*512 + tid;
    if (c==2) ci = 1024 + tid;
    if (ci < 512){
      int line = ci>>3, slot = ci&7;
      int d = slot ^ (line&7);
      int row = 2*line + (d>>2);
      sp[c] = Ab + (size_t)(m0+row)*1536 + (d&3)*16;
    } else if (ci < 1280){
      int i = ci - 512;
      int line = i>>3, slot = i&7;
      int d = slot ^ (line&7);
      int row = 2*line + (d>>2);
      sp[c] = Bb + (size_t)(n0+row)*1536 + (d&3)*16;
    } else {
      sp[c] = Ab;
    }
    ldst[c] = ci*16;
  }

  const int sl = (((fr&1)<<2) + fg) ^ (fr>>1);
  const int aoff = (fr&~1)*64 + sl*16 + wm*4096;
  const int boff = 8192 + (fr&~1)*64 + sl*16 + wn*3072;

  f32x4 zz = {0.f,0.f,0.f,0.f};
  f32x4 acc[4][3];
  #pragma unroll
  for (int i=0;i<4;++i)
    #pragma unroll
    for (int j=0;j<3;++j) acc[i][j]=zz;

  auto STAGE = [&](int t, int b){
    char* dst0 = (char*)P[b];
    #pragma unroll
    for (int c=0;c<3;++c){
      if (c==2 && wid>=4) break;
      __builtin_amdgcn_global_load_lds((const gbl_u32*)(sp[c] + (size_t)t*64),
        (lds_u32*)(dst0 + ldst[c]), 16, 0, 0);
    }
  };
  auto COMPUTE = [&](int b){
    const char* pb = (const char*)P[b];
    bf16x8 bfr[3];
    #pragma unroll
    for (int nt=0;nt<3;++nt)
      bfr[nt] = *(const bf16x8*)(pb + boff + nt*1024);
    #pragma unroll
    for (int mt=0;mt<4;++mt){
      bf16x8 af = *(const bf16x8*)(pb + aoff + mt*1024);
      #pragma unroll
      for (int nt=0;nt<3;++nt)
        acc[mt][nt] = MFMA16(af, bfr[nt], acc[mt][nt]);
    }
  };

  STAGE(0, 0); STAGE(1, 1);
  int cb = 0;
  for (int t=0; t<24; ++t){
    if (t < 23){ if (wid < 4) WAIT3; else WAIT2; } else WAIT0;
    BARR; SCHED;
    if (t < 22){
      int sb = cb + 2; if (sb >= 3) sb -= 3;
      STAGE(t+2, sb);
    }
    __builtin_amdgcn_s_setprio(1);
    COMPUTE(cb);
    __builtin_amdgcn_s_setprio(0);
    cb = (cb == 2) ? 0 : cb + 1;
  }

  const int seg = nb/4;
  const float* bias = seg==0?bq: seg==1?bk:bvv;
  const float sc = (seg==0) ? QSCALE : 1.0f;
  if (seg < 2){
    u16* O = seg==0?Oq:Ok;
    #pragma unroll
    for (int mt=0;mt<4;++mt){
      #pragma unroll
      for (int nt=0;nt<3;++nt){
        int colw = n0 + wn*48 + nt*16 + fr - seg*768;
        float bz = bias[colw];
        int hh = colw>>6, d = colw&63;
        #pragma unroll
        for (int rr=0;rr<4;++rr){
          int row = m0 + wm*64 + mt*16 + fg*4 + rr;
          int b = row>>10, nn = row&1023;
          O[((size_t)(b*12+hh)<<16) + (size_t)nn*64 + d] = f2bf((acc[mt][nt][rr] + bz) * sc);
        }
      }
    }
  } else {
    #pragma unroll
    for (int mt=0;mt<4;++mt){
      #pragma unroll
      for (int nt=0;nt<3;++nt){
        int colw = n0 + wn*48 + nt*16 + fr - 1536;
        float bz = bias[colw];
        int hh = colw>>6, d = colw&63;
        int row0 = m0 + wm*64 + mt*16 + fg*4;
        int b = row0>>10, nn = row0&1023;
        union { u16 h[4]; u64 q; } pk;
        #pragma unroll
        for (int rr=0;rr<4;++rr) pk.h[rr] = f2bf(acc[mt][nt][rr] + bz);
        *(u64*)&Ov[((size_t)(b*12+hh)<<16) + (size_t)d*1024 + nn] = pk.q;
      }
    }
  }
}

// ---- O-projection GEMM: 128x192 tile, 8 waves, 256 blocks = 1/CU ----
__global__ __launch_bounds__(512) void mm_o(const u16* __restrict__ A, const u16* __restrict__ Bp,
                                            const float* __restrict__ bias, float* __restrict__ O)
{
  __shared__ u16 P[3][10240];                 // 3 x 20KB
  const int bid = blockIdx.x;                 // 256
  const int sid = (bid & 7)*32 + (bid >> 3);  // XCD swizzle, m-major per XCD
  const int mb = sid/4, nb = sid & 3;
  const int m0 = mb*128, n0 = nb*192;
  const int tid = threadIdx.x;                // 0..511
  const int lane = tid&63, wid = tid>>6;
  const int wm = wid>>2, wn = wid&3;          // wave tile 64x48
  const int fr = lane&15, fg = lane>>4;

  const char* Ab = (const char*)A;
  const char* Bb = (const char*)Bp;
  const char* sp[3];
  int ldst[3];
  #pragma unroll
  for (int c=0;c<3;++c){
    int ci = c*512 + tid;
    if (c==2) ci = 1024 + tid;
    if (ci < 512){
      int line = ci>>3, slot = ci&7;
      int d = slot ^ (line&7);
      int row = 2*line + (d>>2);
      sp[c] = Ab + (size_t)(m0+row)*1536 + (d&3)*16;
    } else if (ci < 1280){
      int i = ci - 512;
      int line = i>>3, slot = i&7;
      int d = slot ^ (line&7);
      int row = 2*line + (d>>2);
      sp[c] = Bb + (size_t)(n0+row)*1536 + (d&3)*16;
    } else {
      sp[c] = Ab;
    }
    ldst[c] = ci*16;
  }

  const int sl = (((fr&1)<<2) + fg) ^ (fr>>1);
  const int aoff = (fr&~1)*64 + sl*16 + wm*4096;
  const int boff = 8192 + (fr&~1)*64 + sl*16 + wn*3072;

  f32x4 zz = {0.f,0.f,0.f,0.f};
  f32x4 acc[4][3];
  #pragma unroll
  for (int i=0;i<4;++i)
    #pragma unroll
    for (int j=0;j<3;++j) acc[i][j]=zz;

  auto STAGE = [&](int t, int b){
    char* dst0 = (char*)P[b];
    #pragma unroll
    for (int c=0;c<3;++c){
      if (c==2 && wid>=4) break;
      __builtin_amdgcn_global_load_lds((const gbl_u32*)(sp[c] + (size_t)t*64),
        (lds_u32*)(dst0 + ldst[c]), 16, 0, 0);
    }
  };
  auto COMPUTE = [&](int b){
    const char* pb = (const char*)P[b];
    bf16x8 bfr[3];
    #pragma unroll
    for (int nt=0;nt<3;++nt)
      bfr[nt] = *(const bf16x8*)(pb + boff + nt*1024);
    #pragma unroll
    for (int mt=0;mt<4;++mt){
      bf16x8 af = *(const bf16x8*)(pb + aoff + mt*1024);
      #pragma unroll
      for (int nt=0;nt<3;++nt)
        acc[mt][nt] = MFMA16(af, bfr[nt], acc[mt][nt]);
    }
  };

  STAGE(0, 0); STAGE(1, 1);
  int cb = 0;
  for (int t=0; t<24; ++t){
    if (t < 23){ if (wid < 4) WAIT3; else WAIT2; } else WAIT0;
    BARR; SCHED;
    if (t < 22){
      int sb = cb + 2; if (sb >= 3) sb -= 3;
      STAGE(t+2, sb);
    }
    __builtin_amdgcn_s_setprio(1);
    COMPUTE(cb);
    __builtin_amdgcn_s_setprio(0);
    cb = (cb == 2) ? 0 : cb + 1;
  }

  #pragma unroll
  for (int mt=0;mt<4;++mt){
    #pragma unroll
    for (int nt=0;nt<3;++nt){
      int colb = n0 + wn*48 + nt*16 + fr;
      float bz = bias[colb];
      #pragma unroll
      for (int rr=0;rr<4;++rr){
        int row = m0 + wm*64 + mt*16 + fg*4 + rr;
        O[(size_t)row*768 + colb] = acc[mt][nt][rr] + bz;
      }
    }
  }
}

// ---- MFMA flash attention: 32x32 MFMA, P fully in-register via permlane32_swap ----
__global__ __launch_bounds__(256, 3) void attn(const u16* __restrict__ qh, const u16* __restrict__ kh,
                                               const u16* __restrict__ vh, u16* __restrict__ ch)
{
  __shared__ u16 Kb[2][4096];          // 16KB
  __shared__ u16 Vb[2][4096];          // 16KB
  const int tid=threadIdx.x, w=tid>>6, lane=tid&63;
  const int l31 = lane&31, h = lane>>5;
  const int bh=blockIdx.x, qt=blockIdx.y;
  const size_t base=(size_t)bh<<16;
  const int q0=qt*128 + w*32;

  const char* kbase = (const char*)(kh + base);
  const char* vbase = (const char*)(vh + base);

  int koff[2], voff[2];
  #pragma unroll
  for (int c=0;c<2;++c){
    int ci = c*256 + tid;
    int row = ci>>3;
    int colp = ((ci&7)*16) ^ ((row&7)<<4);
    koff[c] = row*128  + colp;
    voff[c] = row*2048 + colp;
  }

  bf16x8 qf[4];
  #pragma unroll
  for (int ks=0;ks<4;++ks)
    qf[ks] = *(const bf16x8*)&qh[base + (size_t)(q0+l31)*64 + ks*16 + h*8];

  const int swz3 = (lane&7)<<4;
  const int dbase = (h<<4) ^ swz3;
  const int krow = l31*128;

  const short one_bf = (short)0x3F80;
  bf16x8 ones = {one_bf,one_bf,one_bf,one_bf,one_bf,one_bf,one_bf,one_bf};

  f32x16 z16 = {0.f,0.f,0.f,0.f,0.f,0.f,0.f,0.f,0.f,0.f,0.f,0.f,0.f,0.f,0.f,0.f};
  f32x16 o0 = z16, o1 = z16, ol = z16;

  {
    #pragma unroll
    for (int c=0;c<2;++c){
      __builtin_amdgcn_global_load_lds((const gbl_u32*)(kbase + koff[c]),
        (lds_u32*)((char*)&Kb[0][0] + c*4096 + w*1024), 16, 0, 0);
      __builtin_amdgcn_global_load_lds((const gbl_u32*)(vbase + voff[c]),
        (lds_u32*)((char*)&Vb[0][0] + c*4096 + w*1024), 16, 0, 0);
    }
  }
  __syncthreads();

  for (int kt=0; kt<16; ++kt){
    const int buf = kt & 1;
    {
      const int ktn = (kt+1) & 15;
      const char* kt_ = kbase + ktn*8192;
      const char* vt_ = vbase + ktn*128;
      #pragma unroll
      for (int c=0;c<2;++c){
        __builtin_amdgcn_global_load_lds((const gbl_u32*)(kt_ + koff[c]),
          (lds_u32*)((char*)&Kb[buf^1][0] + c*4096 + w*1024), 16, 0, 0);
        __builtin_amdgcn_global_load_lds((const gbl_u32*)(vt_ + voff[c]),
          (lds_u32*)((char*)&Vb[buf^1][0] + c*4096 + w*1024), 16, 0, 0);
      }
    }

    const char* kb_ = (const char*)&Kb[buf][0];
    f32x16 s0 = z16, s1 = z16;
    __builtin_amdgcn_s_setprio(1);
    #pragma unroll
    for (int ks=0;ks<4;++ks){
      int db = dbase ^ (ks<<5);
      bf16x8 kf0 = *(const bf16x8*)(kb_ + krow + db);
      bf16x8 kf1 = *(const bf16x8*)(kb_ + 4096 + krow + db);
      s0 = MFMA32(kf0, qf[ks], s0);
      s1 = MFMA32(kf1, qf[ks], s1);
    }
    __builtin_amdgcn_s_setprio(0);

    bf16x8 paf[2][2];
    #pragma unroll
    for (int kbi=0;kbi<2;++kbi){
      const f32x16& sb = kbi ? s1 : s0;
      #pragma unroll
      for (int kp=0;kp<2;++kp){
        float e0 = __builtin_amdgcn_exp2f(sb[kp*8+0]);
        float e1 = __builtin_amdgcn_exp2f(sb[kp*8+1]);
        float e2 = __builtin_amdgcn_exp2f(sb[kp*8+2]);
        float e3 = __builtin_amdgcn_exp2f(sb[kp*8+3]);
        float e4 = __builtin_amdgcn_exp2f(sb[kp*8+4]);
        float e5 = __builtin_amdgcn_exp2f(sb[kp*8+5]);
        float e6 = __builtin_amdgcn_exp2f(sb[kp*8+6]);
        float e7 = __builtin_amdgcn_exp2f(sb[kp*8+7]);
        u32 x, y, uu, vv;
        asm("v_cvt_pk_bf16_f32 %0, %1, %2" : "=v"(x)  : "v"(e0), "v"(e1));
        asm("v_cvt_pk_bf16_f32 %0, %1, %2" : "=v"(y)  : "v"(e2), "v"(e3));
        asm("v_cvt_pk_bf16_f32 %0, %1, %2" : "=v"(uu) : "v"(e4), "v"(e5));
        asm("v_cvt_pk_bf16_f32 %0, %1, %2" : "=v"(vv) : "v"(e6), "v"(e7));
        asm volatile("v_permlane32_swap_b32 %0, %1" : "+v"(x), "+v"(uu));
        asm volatile("v_permlane32_swap_b32 %0, %1" : "+v"(y), "+v"(vv));
        union { u32 u[4]; bf16x8 v; } fx;
        fx.u[0]=x; fx.u[1]=y; fx.u[2]=uu; fx.u[3]=vv;
        paf[kbi][kp] = fx.v;
      }
    }

    const char* vb_ = (const char*)&Vb[buf][0];
    __builtin_amdgcn_s_setprio(1);
    #pragma unroll
    for (int kbi=0;kbi<2;++kbi){
      #pragma unroll
      for (int kp=0;kp<2;++kp){
        int vcol = dbase ^ (kp<<5) ^ (kbi<<6);
        bf16x8 vf0 = *(const bf16x8*)(vb_ + l31*128 + vcol);
        bf16x8 vf1 = *(const bf16x8*)(vb_ + (32+l31)*128 + vcol);
        o0 = MFMA32(paf[kbi][kp], vf0, o0);
        o1 = MFMA32(paf[kbi][kp], vf1, o1);
        ol = MFMA32(paf[kbi][kp], ones, ol);
      }
    }
    __builtin_amdgcn_s_setprio(0);

    __syncthreads();
  }

  const int b=bh/12, hd=bh%12;
  float inv[16];
  #pragma unroll
  for (int rg=0;rg<16;++rg) inv[rg] = 1.0f / ol[rg];
  #pragma unroll
  for (int nt=0;nt<2;++nt){
    #pragma unroll
    for (int rg=0;rg<16;++rg){
      int q = q0 + (rg&3) + 8*(rg>>2) + 4*h;
      int d = nt*32 + l31;
      float val = (nt ? o1[rg] : o0[rg]) * inv[rg];
      ch[((size_t)b*1024 + q)*768 + hd*64 + d] = f2bf(val);
    }
  }
}

extern "C" void kernel_launch(void* const* d_in, const int* in_sizes, int n_in,
                              void* d_out, int out_size, void* d_ws, size_t ws_size,
                              hipStream_t stream) {
  const float* hs = (const float*)d_in[0];
  const float* Wq = (const float*)d_in[1];
  const float* bq = (const float*)d_in[2];
  const float* Wk = (const float*)d_in[3];
  const float* bk = (const float*)d_in[4];
  const float* Wv = (const float*)d_in[5];
  const float* bv = (const float*)d_in[6];
  const float* Wo = (const float*)d_in[7];
  const float* bo = (const float*)d_in[8];
  float* out = (float*)d_out;

  const size_t PS = (size_t)8192*768;
  u16* ws16  = (u16*)d_ws;
  u16* hs_bf = ws16;                        // reused as c_hi after mm_qkv
  u16* q_bf  = ws16 + PS;
  u16* k_bf  = ws16 + 2*PS;
  u16* v_bf  = ws16 + 3*PS;                 // transposed per head [bh][d][n]
  u16* wqkv  = ws16 + 4*PS;
  u16* woh   = wqkv + 3*589824;
  u16* c_hi  = hs_bf;

  dim3 blk(256);
  cvt_all<<<3072 + 4*288, blk, 0, stream>>>(hs, Wq, Wk, Wv, Wo, hs_bf, wqkv, woh);
  mm_qkv<<<768, dim3(512), 0, stream>>>(hs_bf, wqkv, bq, bk, bv, q_bf, k_bf, v_bf);
  attn<<<dim3(96,8), blk, 0, stream>>>(q_bf, k_bf, v_bf, c_hi);
  mm_o<<<256, dim3(512), 0, stream>>>(c_hi, woh, bo, out);
}